// Round 1
// baseline (475.611 us; speedup 1.0000x reference)
//
#include <hip/hip_runtime.h>

#define BB 8
#define NN 16384
#define CC 256
#define DD 32
#define EPSF 1e-6f

// ws layout (floats)
#define QBUF_FLOATS (2ull*BB*NN*DD)            // 8,388,608 floats (32 MiB)
#define ACC_STRIDE 8480                         // per (s,b): KX[32][256], xsum[256], ksum0[32]
#define ACC_OFF QBUF_FLOATS
#define ACC_FLOATS (16*ACC_STRIDE)
#define FIN_OFF (ACC_OFF + ACC_FLOATS)
#define FIN_STRIDE 8480                         // per (s,b): mat[32][256], vsum[256], ksum_eps[32]

// ---------------------------------------------------------------------------
// Kernel 1: per (block-of-positions, batch, stream):
//   K,Q = [Wk;Wq] @ X^T (normalized per position), Q -> global scratch,
//   accumulate KX += K @ X, xsum += col-sums(X), ksum0 += row-sums(K).
// ---------------------------------------------------------------------------
__global__ __launch_bounds__(256, 2)
void k1_proj(const float* __restrict__ x, const float* __restrict__ y,
             const float* __restrict__ Wk, const float* __restrict__ bk,
             const float* __restrict__ Wq, const float* __restrict__ bq,
             const float* __restrict__ Wky, const float* __restrict__ bky,
             const float* __restrict__ Wqy, const float* __restrict__ bqy,
             float* __restrict__ qbuf, float* __restrict__ acc)
{
    const int b = blockIdx.y, s = blockIdx.z;
    const float* __restrict__ src = (s ? y : x) + (size_t)b * NN * CC;
    const float* __restrict__ Wk_ = s ? Wky : Wk;
    const float* __restrict__ Wq_ = s ? Wqy : Wq;
    const float* __restrict__ bk_ = s ? bky : bk;
    const float* __restrict__ bq_ = s ? bqy : bq;
    float* __restrict__ qb = qbuf + (size_t)(s*BB + b) * NN * DD;
    float* __restrict__ accsb = acc + (size_t)(s*BB + b) * ACC_STRIDE;

    __shared__ float Xs[64][260];   // 66,560 B
    __shared__ float Ks[32][68];    //  8,704 B
    __shared__ float red[16][66];   //  4,224 B
    __shared__ float nrm[2][64];    //    512 B

    const int tid = threadIdx.x;
    // GEMM1 mapping: out tile [64 rows(d)] x [64 pos]
    const int dg = tid >> 4;            // 0..15
    const int pg = tid & 15;            // 0..15
    const bool isK = (dg < 8);
    const float* __restrict__ wbase = isK ? Wk_ : Wq_;
    const int drow = (isK ? dg : dg - 8) * 4;
    float bias0 = (isK ? bk_ : bq_)[drow + 0];
    float bias1 = (isK ? bk_ : bq_)[drow + 1];
    float bias2 = (isK ? bk_ : bq_)[drow + 2];
    float bias3 = (isK ? bk_ : bq_)[drow + 3];
    // GEMM2 mapping: out tile [32 d] x [256 c], 4d x 8c per thread
    const int dg2 = tid >> 5;           // 0..7
    const int cg  = tid & 31;           // 0..31
    const int cA = cg * 4, cB = 128 + cg * 4;

    float kx[4][8];
    #pragma unroll
    for (int i = 0; i < 4; ++i)
        #pragma unroll
        for (int m = 0; m < 8; ++m) kx[i][m] = 0.f;
    float ksum_d = 0.f;
    float xsum_c = 0.f;

    for (int ch = 0; ch < 4; ++ch) {
        const int p0 = (blockIdx.x * 4 + ch) * 64;
        // ---- stage X chunk: 64 x 256
        {
            const float* __restrict__ sp = src + (size_t)p0 * CC;
            #pragma unroll
            for (int m = 0; m < 16; ++m) {
                int flat = m * 1024 + tid * 4;
                int r = flat >> 8, c = flat & 255;
                float4 v = *(const float4*)(sp + flat);
                *(float4*)&Xs[r][c] = v;
            }
        }
        __syncthreads();
        // ---- GEMM1: r1[i][j] = bias + sum_c W[drow+i][c] * Xs[pg+16j][c]
        float r1[4][4];
        #pragma unroll
        for (int j = 0; j < 4; ++j) { r1[0][j]=bias0; r1[1][j]=bias1; r1[2][j]=bias2; r1[3][j]=bias3; }
        #pragma unroll 2
        for (int c4 = 0; c4 < 256; c4 += 4) {
            float4 w0 = *(const float4*)(wbase + (size_t)(drow+0)*256 + c4);
            float4 w1 = *(const float4*)(wbase + (size_t)(drow+1)*256 + c4);
            float4 w2 = *(const float4*)(wbase + (size_t)(drow+2)*256 + c4);
            float4 w3 = *(const float4*)(wbase + (size_t)(drow+3)*256 + c4);
            #pragma unroll
            for (int j = 0; j < 4; ++j) {
                float4 xv = *(const float4*)&Xs[pg + 16*j][c4];
                r1[0][j] += w0.x*xv.x + w0.y*xv.y + w0.z*xv.z + w0.w*xv.w;
                r1[1][j] += w1.x*xv.x + w1.y*xv.y + w1.z*xv.z + w1.w*xv.w;
                r1[2][j] += w2.x*xv.x + w2.y*xv.y + w2.z*xv.z + w2.w*xv.w;
                r1[3][j] += w3.x*xv.x + w3.y*xv.y + w3.z*xv.z + w3.w*xv.w;
            }
        }
        // ---- per-position squared partials for norms
        #pragma unroll
        for (int j = 0; j < 4; ++j) {
            float ss = r1[0][j]*r1[0][j] + r1[1][j]*r1[1][j] + r1[2][j]*r1[2][j] + r1[3][j]*r1[3][j];
            red[dg][pg + 16*j] = ss;
        }
        __syncthreads();
        if (tid < 128) {
            int h = tid >> 6, p = tid & 63;
            float ssum = 0.f;
            #pragma unroll
            for (int g = 0; g < 8; ++g) ssum += red[h*8 + g][p];
            nrm[h][p] = rsqrtf(ssum);
        }
        __syncthreads();
        if (isK) {
            #pragma unroll
            for (int j = 0; j < 4; ++j) {
                float nv = nrm[0][pg + 16*j];
                Ks[drow+0][pg+16*j] = r1[0][j]*nv;
                Ks[drow+1][pg+16*j] = r1[1][j]*nv;
                Ks[drow+2][pg+16*j] = r1[2][j]*nv;
                Ks[drow+3][pg+16*j] = r1[3][j]*nv;
            }
        } else {
            #pragma unroll
            for (int j = 0; j < 4; ++j) {
                int p = pg + 16*j;
                float nv = nrm[1][p];
                float4 qv = make_float4(r1[0][j]*nv, r1[1][j]*nv, r1[2][j]*nv, r1[3][j]*nv);
                *(float4*)(qb + (size_t)(p0 + p) * DD + drow) = qv;
            }
        }
        // ---- xsum partial (Xs still valid)
        #pragma unroll 8
        for (int p = 0; p < 64; ++p) xsum_c += Xs[p][tid];
        __syncthreads();   // Ks ready
        // ---- ksum partial
        if (tid < 32) {
            float sK = 0.f;
            #pragma unroll 8
            for (int p = 0; p < 64; ++p) sK += Ks[tid][p];
            ksum_d += sK;
        }
        // ---- GEMM2: kx[i][*] += sum_p Ks[dg2*4+i][p] * Xs[p][c*]
        #pragma unroll 2
        for (int p4 = 0; p4 < 64; p4 += 4) {
            float4 kk0 = *(const float4*)&Ks[dg2*4+0][p4];
            float4 kk1 = *(const float4*)&Ks[dg2*4+1][p4];
            float4 kk2 = *(const float4*)&Ks[dg2*4+2][p4];
            float4 kk3 = *(const float4*)&Ks[dg2*4+3][p4];
            #pragma unroll
            for (int u = 0; u < 4; ++u) {
                float4 xa = *(const float4*)&Xs[p4+u][cA];
                float4 xb = *(const float4*)&Xs[p4+u][cB];
                float k0 = (u==0)?kk0.x:(u==1)?kk0.y:(u==2)?kk0.z:kk0.w;
                float k1 = (u==0)?kk1.x:(u==1)?kk1.y:(u==2)?kk1.z:kk1.w;
                float k2 = (u==0)?kk2.x:(u==1)?kk2.y:(u==2)?kk2.z:kk2.w;
                float k3 = (u==0)?kk3.x:(u==1)?kk3.y:(u==2)?kk3.z:kk3.w;
                kx[0][0]+=k0*xa.x; kx[0][1]+=k0*xa.y; kx[0][2]+=k0*xa.z; kx[0][3]+=k0*xa.w;
                kx[0][4]+=k0*xb.x; kx[0][5]+=k0*xb.y; kx[0][6]+=k0*xb.z; kx[0][7]+=k0*xb.w;
                kx[1][0]+=k1*xa.x; kx[1][1]+=k1*xa.y; kx[1][2]+=k1*xa.z; kx[1][3]+=k1*xa.w;
                kx[1][4]+=k1*xb.x; kx[1][5]+=k1*xb.y; kx[1][6]+=k1*xb.z; kx[1][7]+=k1*xb.w;
                kx[2][0]+=k2*xa.x; kx[2][1]+=k2*xa.y; kx[2][2]+=k2*xa.z; kx[2][3]+=k2*xa.w;
                kx[2][4]+=k2*xb.x; kx[2][5]+=k2*xb.y; kx[2][6]+=k2*xb.z; kx[2][7]+=k2*xb.w;
                kx[3][0]+=k3*xa.x; kx[3][1]+=k3*xa.y; kx[3][2]+=k3*xa.z; kx[3][3]+=k3*xa.w;
                kx[3][4]+=k3*xb.x; kx[3][5]+=k3*xb.y; kx[3][6]+=k3*xb.z; kx[3][7]+=k3*xb.w;
            }
        }
        __syncthreads();  // before restaging Xs/Ks
    }
    // ---- atomics
    #pragma unroll
    for (int i = 0; i < 4; ++i) {
        int d = dg2*4 + i;
        #pragma unroll
        for (int m = 0; m < 4; ++m) {
            atomicAdd(accsb + d*256 + cA + m, kx[i][m]);
            atomicAdd(accsb + d*256 + cB + m, kx[i][4+m]);
        }
    }
    atomicAdd(accsb + 8192 + tid, xsum_c);
    if (tid < 32) atomicAdd(accsb + 8448 + tid, ksum_d);
}

// ---------------------------------------------------------------------------
// Kernel 2: finalize per (b,s): mat = KX @ Wv^T + ksum0 (x) bv ; vsum = Wv@xsum + N*bv
// ---------------------------------------------------------------------------
__global__ __launch_bounds__(256, 2)
void k2_finalize(const float* __restrict__ Wv, const float* __restrict__ bv,
                 const float* __restrict__ Wvy, const float* __restrict__ bvy,
                 const float* __restrict__ acc, float* __restrict__ fin)
{
    const int b = blockIdx.x, s = blockIdx.y;
    const float* __restrict__ Wv_ = s ? Wvy : Wv;
    const float* __restrict__ bv_ = s ? bvy : bv;
    const float* __restrict__ a = acc + (size_t)(s*BB + b) * ACC_STRIDE;
    float* __restrict__ f = fin + (size_t)(s*BB + b) * FIN_STRIDE;

    __shared__ float KXt[256][36];   // transposed KX: [c'][d]
    __shared__ float xs[256];
    __shared__ float ks0[32];

    const int tid = threadIdx.x;
    for (int d = 0; d < 32; ++d) KXt[tid][d] = a[d*256 + tid];
    xs[tid] = a[8192 + tid];
    if (tid < 32) { float v = a[8448 + tid]; ks0[tid] = v; f[8448 + tid] = v + EPSF; }
    __syncthreads();

    const int dh = tid >> 7;                 // d-range dh*16..+15
    const int c0 = (tid & 127) * 2;
    float macc[16][2];
    #pragma unroll
    for (int i = 0; i < 16; ++i) { macc[i][0]=0.f; macc[i][1]=0.f; }
    float v0 = 0.f, v1 = 0.f;

    for (int k4 = 0; k4 < 256; k4 += 4) {
        float4 wa = *(const float4*)(Wv_ + (size_t)c0*256 + k4);
        float4 wb = *(const float4*)(Wv_ + (size_t)(c0+1)*256 + k4);
        float4 xv = *(const float4*)&xs[k4];
        v0 += wa.x*xv.x + wa.y*xv.y + wa.z*xv.z + wa.w*xv.w;
        v1 += wb.x*xv.x + wb.y*xv.y + wb.z*xv.z + wb.w*xv.w;
        #pragma unroll
        for (int u = 0; u < 4; ++u) {
            float wau = (u==0)?wa.x:(u==1)?wa.y:(u==2)?wa.z:wa.w;
            float wbu = (u==0)?wb.x:(u==1)?wb.y:(u==2)?wb.z:wb.w;
            #pragma unroll
            for (int i4 = 0; i4 < 16; i4 += 4) {
                float4 kxv = *(const float4*)&KXt[k4+u][dh*16 + i4];
                macc[i4+0][0] += kxv.x*wau; macc[i4+0][1] += kxv.x*wbu;
                macc[i4+1][0] += kxv.y*wau; macc[i4+1][1] += kxv.y*wbu;
                macc[i4+2][0] += kxv.z*wau; macc[i4+2][1] += kxv.z*wbu;
                macc[i4+3][0] += kxv.w*wau; macc[i4+3][1] += kxv.w*wbu;
            }
        }
    }
    float bvc0 = bv_[c0], bvc1 = bv_[c0+1];
    if (dh == 0) {
        f[8192 + c0]     = v0 + (float)NN * bvc0;
        f[8192 + c0 + 1] = v1 + (float)NN * bvc1;
    }
    #pragma unroll
    for (int i = 0; i < 16; ++i) {
        int d = dh*16 + i;
        f[d*256 + c0]     = macc[i][0] + ks0[d]*bvc0;
        f[d*256 + c0 + 1] = macc[i][1] + ks0[d]*bvc1;
    }
}

// ---------------------------------------------------------------------------
// Kernel 3: outputs. Per block: batch b, 64 positions, BOTH streams.
//   F[r][c] = sv[r]*vsum_s[c] + sum_k At[k][r]*Ms[k][c],  Ms = [mat; maty]
// ---------------------------------------------------------------------------
__global__ __launch_bounds__(512, 2)
void k3_output(const float* __restrict__ qbuf, const float* __restrict__ fin,
               const float* __restrict__ g_gamma, const float* __restrict__ g_gammay,
               const float* __restrict__ g_gammacx, const float* __restrict__ g_gammacy,
               const float* __restrict__ g_wx1, const float* __restrict__ g_wx2,
               const float* __restrict__ g_wy1, const float* __restrict__ g_wy2,
               float* __restrict__ out)
{
    const int b = blockIdx.y;
    const int p0 = blockIdx.x * 64;
    const float* __restrict__ fx_ = fin + (size_t)(0*BB + b) * FIN_STRIDE;
    const float* __restrict__ fy_ = fin + (size_t)(1*BB + b) * FIN_STRIDE;

    __shared__ float Ms[64][260];   // 66,560 B : rows 0..31 = mat(x), 32..63 = maty
    __shared__ float At[64][132];   // 33,792 B : A^T[k][row], rows 0..63 x, 64..127 y
    __shared__ float vs[2][256];
    __shared__ float ksl[2][32];    // Ksum_eps, Kysum_eps
    __shared__ float sv[128];

    const int tid = threadIdx.x;
    if (tid < 256) { vs[0][tid] = fx_[8192 + tid]; vs[1][tid] = fy_[8192 + tid]; }
    else if (tid < 320) { int t = tid - 256; ksl[t >> 5][t & 31] = ((t < 32) ? fx_ : fy_)[8448 + (t & 31)]; }
    __syncthreads();

    if (tid < 128) {
        const int str = tid >> 6;
        const int p = p0 + (tid & 63);
        const float* __restrict__ qp = qbuf + ((size_t)(str*BB + b) * NN + p) * DD;
        float q[32];
        float ss = 0.f;
        #pragma unroll
        for (int m = 0; m < 8; ++m) {
            float4 v = *(const float4*)(qp + m*4);
            q[m*4+0]=v.x; q[m*4+1]=v.y; q[m*4+2]=v.z; q[m*4+3]=v.w;
            ss += v.x*v.x + v.y*v.y + v.z*v.z + v.w*v.w;
        }
        float qn = rsqrtf(ss);
        float dK = 0.f, dKy = 0.f;
        #pragma unroll
        for (int d = 0; d < 32; ++d) { dK += q[d]*ksl[0][d]; dKy += q[d]*ksl[1][d]; }
        dK *= qn; dKy *= qn;
        float clo, chi, svr;
        if (str == 0) {
            float t1 = 1.f / ((float)NN + dK);
            float t2 = 1.f / ((float)NN + dKy);
            float a1 = g_gamma[0]   * g_wx1[0] * t1;
            float a2 = g_gammacx[0] * g_wx2[0] * t2;
            clo = a1 * qn; chi = a2 * qn; svr = a1 + a2;
        } else {
            float ty1 = 1.f / ((float)NN + dKy);  // Qy . Kysum
            float ty2 = 1.f / ((float)NN + dK);   // Qy . Ksum
            float b1 = g_gammay[0]  * g_wy1[0] * ty1;  // maty half
            float b2 = g_gammacy[0] * g_wy2[0] * ty2;  // mat half
            clo = b2 * qn; chi = b1 * qn; svr = b1 + b2;
        }
        sv[tid] = svr;
        #pragma unroll
        for (int k = 0; k < 32; ++k) At[k][tid]      = clo * q[k];
        #pragma unroll
        for (int k = 0; k < 32; ++k) At[32 + k][tid] = chi * q[k];
    } else {
        for (int f4 = tid - 128; f4 < 4096; f4 += 384) {
            int flat = f4 * 4;
            int k = flat >> 8, c = flat & 255;
            const float* __restrict__ srcp = (k < 32) ? (fx_ + k*256 + c) : (fy_ + (k-32)*256 + c);
            *(float4*)&Ms[k][c] = *(const float4*)srcp;
        }
    }
    __syncthreads();

    const int rg = tid >> 5, cg = tid & 31;
    const int r0 = rg * 8;
    const int cA = cg * 4, cB2 = 128 + cg * 4;
    float accr[8][8];
    #pragma unroll
    for (int i = 0; i < 8; ++i)
        #pragma unroll
        for (int m = 0; m < 8; ++m) accr[i][m] = 0.f;

    #pragma unroll 2
    for (int k = 0; k < 64; ++k) {
        float4 a0 = *(const float4*)&At[k][r0];
        float4 a1 = *(const float4*)&At[k][r0 + 4];
        float4 m0 = *(const float4*)&Ms[k][cA];
        float4 m1 = *(const float4*)&Ms[k][cB2];
        float av[8] = {a0.x, a0.y, a0.z, a0.w, a1.x, a1.y, a1.z, a1.w};
        #pragma unroll
        for (int i = 0; i < 8; ++i) {
            accr[i][0] += av[i]*m0.x; accr[i][1] += av[i]*m0.y;
            accr[i][2] += av[i]*m0.z; accr[i][3] += av[i]*m0.w;
            accr[i][4] += av[i]*m1.x; accr[i][5] += av[i]*m1.y;
            accr[i][6] += av[i]*m1.z; accr[i][7] += av[i]*m1.w;
        }
    }

    float* __restrict__ fxout = out;
    float* __restrict__ fyout = out + (size_t)BB * NN * CC;
    const int str = rg >> 3;
    const float* __restrict__ vrow = vs[str];
    float4 vA = *(const float4*)&vrow[cA];
    float4 vB = *(const float4*)&vrow[cB2];
    #pragma unroll
    for (int i = 0; i < 8; ++i) {
        int r = r0 + i;
        int p = p0 + (r & 63);
        float svr = sv[r];
        float4 o0 = make_float4(accr[i][0] + svr*vA.x, accr[i][1] + svr*vA.y,
                                accr[i][2] + svr*vA.z, accr[i][3] + svr*vA.w);
        float4 o1 = make_float4(accr[i][4] + svr*vB.x, accr[i][5] + svr*vB.y,
                                accr[i][6] + svr*vB.z, accr[i][7] + svr*vB.w);
        float* __restrict__ op = (str ? fyout : fxout) + ((size_t)b * NN + p) * CC;
        *(float4*)(op + cA)  = o0;
        *(float4*)(op + cB2) = o1;
    }
}

extern "C" void kernel_launch(void* const* d_in, const int* in_sizes, int n_in,
                              void* d_out, int out_size, void* d_ws, size_t ws_size,
                              hipStream_t stream)
{
    (void)in_sizes; (void)n_in; (void)out_size; (void)ws_size;
    const float* x   = (const float*)d_in[0];
    const float* y   = (const float*)d_in[1];
    const float* Wq  = (const float*)d_in[2];
    const float* bq  = (const float*)d_in[3];
    const float* Wk  = (const float*)d_in[4];
    const float* bk  = (const float*)d_in[5];
    const float* Wv  = (const float*)d_in[6];
    const float* bv  = (const float*)d_in[7];
    const float* Wqy = (const float*)d_in[8];
    const float* bqy = (const float*)d_in[9];
    const float* Wky = (const float*)d_in[10];
    const float* bky = (const float*)d_in[11];
    const float* Wvy = (const float*)d_in[12];
    const float* bvy = (const float*)d_in[13];

    float* ws   = (float*)d_ws;
    float* qbuf = ws;
    float* acc  = ws + ACC_OFF;
    float* fin  = ws + FIN_OFF;

    hipMemsetAsync(acc, 0, ACC_FLOATS * sizeof(float), stream);

    k1_proj<<<dim3(64, BB, 2), 256, 0, stream>>>(x, y, Wk, bk, Wq, bq, Wky, bky, Wqy, bqy, qbuf, acc);
    k2_finalize<<<dim3(BB, 2), 256, 0, stream>>>(Wv, bv, Wvy, bvy, acc, fin);
    k3_output<<<dim3(NN/64, BB), 512, 0, stream>>>(qbuf, fin,
        (const float*)d_in[14], (const float*)d_in[15], (const float*)d_in[16], (const float*)d_in[17],
        (const float*)d_in[18], (const float*)d_in[19], (const float*)d_in[20], (const float*)d_in[21],
        (float*)d_out);
}